// Round 4
// baseline (101.627 us; speedup 1.0000x reference)
//
#include <hip/hip_runtime.h>

// B=524288 independent attentions over [S=10, D=6].
// out[b,q] = sum_k softmax_k(score[q,k]) * vsum[k]
// score[q,k] = t_q . x_k + a_k  (q-constant terms cancel in softmax; bk, bq.bk
// terms are k-constant or cancel). Precompute folds log2(e) into G and w so the
// softmax exp is a single v_exp_f32 (2^x) per score:
//   G'[d][dp] = log2e * sum_e Wq[e][d] Wk[e][dp]
//   w'[dp]    = log2e * sum_e bq[e]  Wk[e][dp]
//   vsum[k]   = wvs . x_k + bvs   (wvs[d] = sum_e Wv[e][d], bvs = sum_e bv[e])
// ws layout (floats): [0..35] G', [36..41] w', [42..47] wvs, [48] bvs

#define NB 524288
#define S 10
#define D 6
#define TPB 256
#define EPB 128          // elements per block (2 threads per element)
#define XFL (S * D)      // 60 floats per element
#define LDS_FLOATS (EPB * XFL)   // 7680 floats = 30720 B = 30 chunks of 1 KB

__global__ void precompute_kernel(const float* __restrict__ Wk, const float* __restrict__ bk,
                                  const float* __restrict__ Wq, const float* __restrict__ bq,
                                  const float* __restrict__ Wv, const float* __restrict__ bv,
                                  float* __restrict__ ws) {
    const float LOG2E = 1.44269504088896340736f;
    int t = threadIdx.x;
    if (t < 36) {
        int d = t / 6, dp = t % 6;
        float g = 0.f;
        for (int e = 0; e < D; ++e) g += Wq[e * D + d] * Wk[e * D + dp];
        ws[t] = g * LOG2E;
    } else if (t < 42) {
        int dp = t - 36;
        float s = 0.f;
        for (int e = 0; e < D; ++e) s += bq[e] * Wk[e * D + dp];
        ws[t] = s * LOG2E;
    } else if (t < 48) {
        int d = t - 42;
        float s = 0.f;
        for (int e = 0; e < D; ++e) s += Wv[e * D + d];
        ws[t] = s;
    } else if (t == 48) {
        float s = 0.f;
        for (int e = 0; e < D; ++e) s += bv[e];
        ws[t] = s;
    }
}

// (256,4): 128-VGPR budget, 4 blocks/CU (16 waves). Kernel needs ~110 VGPRs.
__global__ __launch_bounds__(TPB, 4) void attn_kernel(const float* __restrict__ x,
                                                      const float* __restrict__ ws,
                                                      float* __restrict__ out) {
    __shared__ float xs[LDS_FLOATS];
    const int t = threadIdx.x;
    const int blk = blockIdx.x;
    const int wave = t >> 6;
    const int lane = t & 63;

    // Async coalesced global->LDS, linear layout: 30 chunks of 1 KB (64 lanes x 16 B).
    // No LDS write instructions, no index divides, no VGPR round-trip.
    const float* gbase = x + (size_t)blk * LDS_FLOATS;
    #pragma unroll
    for (int i = 0; i < 8; ++i) {
        int c = wave + 4 * i;           // wave-uniform chunk id
        if (c < 30) {
            __builtin_amdgcn_global_load_lds(
                (const __attribute__((address_space(1))) void*)(gbase + c * 256 + lane * 4),
                (__attribute__((address_space(3))) void*)(&xs[c * 256 + lane * 4]),
                16, 0, 0);
        }
    }

    // Wave-uniform constants -> s_load / SGPR resident (keeps VGPR pressure low)
    float G[36], w[6], wvs[6];
    #pragma unroll
    for (int i = 0; i < 36; ++i) G[i] = ws[i];
    #pragma unroll
    for (int i = 0; i < 6; ++i) w[i] = ws[36 + i];
    #pragma unroll
    for (int i = 0; i < 6; ++i) wvs[i] = ws[42 + i];
    const float bvs = ws[48];

    __syncthreads();   // drains vmcnt(0) -> staging complete

    const int e = t >> 1;     // local element (pair-lanes broadcast same LDS rows)
    const int h = t & 1;      // which half of the 10 queries

    // Bulk LDS->reg: 15 x ds_read_b128 (base e*240 B is 16B-aligned).
    float xv[XFL];
    const float4* xr = (const float4*)&xs[e * XFL];
    #pragma unroll
    for (int i = 0; i < 15; ++i) {
        float4 v = xr[i];
        xv[4 * i + 0] = v.x;
        xv[4 * i + 1] = v.y;
        xv[4 * i + 2] = v.z;
        xv[4 * i + 3] = v.w;
    }

    // t_q (log2-domain) for this thread's 5 queries — pure register math from here.
    float tq[5][6];
    #pragma unroll
    for (int j = 0; j < 5; ++j) {
        #pragma unroll
        for (int dp = 0; dp < 6; ++dp) {
            float s = 0.f;
            #pragma unroll
            for (int d = 0; d < 6; ++d) s += xv[(h * 5 + j) * 6 + d] * G[d * 6 + dp];
            tq[j][dp] = s;
        }
    }

    float num[5] = {0.f, 0.f, 0.f, 0.f, 0.f};
    float den[5] = {0.f, 0.f, 0.f, 0.f, 0.f};
    #pragma unroll
    for (int k = 0; k < S; ++k) {
        float a = 0.f, vk = bvs;
        #pragma unroll
        for (int d = 0; d < 6; ++d) {
            a += w[d] * xv[k * 6 + d];
            vk += wvs[d] * xv[k * 6 + d];
        }
        #pragma unroll
        for (int j = 0; j < 5; ++j) {
            float s = a;
            #pragma unroll
            for (int d = 0; d < 6; ++d) s += tq[j][d] * xv[k * 6 + d];
            float ex = __builtin_amdgcn_exp2f(s);   // scores pre-scaled by log2e
            den[j] += ex;
            num[j] += ex * vk;
        }
    }

    // Thread's 5 outputs are contiguous: out flat idx = blk*1280 + t*5 + j
    float* op = out + (size_t)blk * (EPB * S) + t * 5;
    #pragma unroll
    for (int j = 0; j < 5; ++j) op[j] = num[j] * __builtin_amdgcn_rcpf(den[j]);
}

extern "C" void kernel_launch(void* const* d_in, const int* in_sizes, int n_in,
                              void* d_out, int out_size, void* d_ws, size_t ws_size,
                              hipStream_t stream) {
    const float* x  = (const float*)d_in[0];
    const float* Wk = (const float*)d_in[1];
    const float* bk = (const float*)d_in[2];
    const float* Wq = (const float*)d_in[3];
    const float* bq = (const float*)d_in[4];
    const float* Wv = (const float*)d_in[5];
    const float* bv = (const float*)d_in[6];
    float* out = (float*)d_out;
    float* ws  = (float*)d_ws;

    precompute_kernel<<<1, 64, 0, stream>>>(Wk, bk, Wq, bq, Wv, bv, ws);
    attn_kernel<<<NB / EPB, TPB, 0, stream>>>(x, ws, out);
}

// Round 5
// 43.639 us; speedup vs baseline: 2.3288x; 2.3288x over previous
//
#include <hip/hip_runtime.h>

// B=524288 independent attentions over [S=10, D=6].
// out[b,q] = sum_k softmax_k(score[q,k]) * vsum[k]
// score[q,k] = t_q . x_k + a_k  (q-constant terms cancel in softmax).
// Precompute folds log2(e) into G and w so softmax exp is a bare v_exp_f32:
//   G'[d][dp] = log2e * sum_e Wq[e][d] Wk[e][dp]
//   w'[dp]    = log2e * sum_e bq[e]  Wk[e][dp]
//   vsum[k]   = wvs . x_k + bvs   (wvs[d] = sum_e Wv[e][d], bvs = sum_e bv[e])
// ws layout (floats): [0..35] G', [36..41] w', [42..47] wvs, [48] bvs
//
// R4 lesson (rule #20): xv[] was indexed with runtime h -> whole array spilled
// to scratch (290 MB WRITE_SIZE). Here every xv[] index is compile-time; the
// runtime-h access goes through LDS instead (dynamic LDS addressing is fine).

#define NB 524288
#define S 10
#define D 6
#define TPB 256
#define EPB 128          // elements per block (2 threads per element)
#define XFL (S * D)      // 60 floats per element
#define LDS_FLOATS (EPB * XFL)   // 7680 floats = 30720 B = 30 chunks of 1 KB

__global__ void precompute_kernel(const float* __restrict__ Wk, const float* __restrict__ bk,
                                  const float* __restrict__ Wq, const float* __restrict__ bq,
                                  const float* __restrict__ Wv, const float* __restrict__ bv,
                                  float* __restrict__ ws) {
    const float LOG2E = 1.44269504088896340736f;
    int t = threadIdx.x;
    if (t < 36) {
        int d = t / 6, dp = t % 6;
        float g = 0.f;
        for (int e = 0; e < D; ++e) g += Wq[e * D + d] * Wk[e * D + dp];
        ws[t] = g * LOG2E;
    } else if (t < 42) {
        int dp = t - 36;
        float s = 0.f;
        for (int e = 0; e < D; ++e) s += bq[e] * Wk[e * D + dp];
        ws[t] = s * LOG2E;
    } else if (t < 48) {
        int d = t - 42;
        float s = 0.f;
        for (int e = 0; e < D; ++e) s += Wv[e * D + d];
        ws[t] = s;
    } else if (t == 48) {
        float s = 0.f;
        for (int e = 0; e < D; ++e) s += bv[e];
        ws[t] = s;
    }
}

// Load a wave-uniform constant and pin it to an SGPR.
__device__ __forceinline__ float sconst(const float* __restrict__ p, int i) {
    return __int_as_float(__builtin_amdgcn_readfirstlane(__float_as_int(p[i])));
}

// (256,4): 128-VGPR budget (4 waves/SIMD). Kernel needs ~110 VGPRs.
__global__ __launch_bounds__(TPB, 4) void attn_kernel(const float* __restrict__ x,
                                                      const float* __restrict__ ws,
                                                      float* __restrict__ out) {
    __shared__ float xs[LDS_FLOATS];
    const int t = threadIdx.x;
    const int blk = blockIdx.x;
    const int wave = t >> 6;
    const int lane = t & 63;

    // Async coalesced global->LDS, linear layout: 30 chunks of 1 KB (64 lanes x 16 B).
    const float* gbase = x + (size_t)blk * LDS_FLOATS;
    #pragma unroll
    for (int i = 0; i < 8; ++i) {
        int c = wave + 4 * i;           // wave-uniform chunk id
        if (c < 30) {
            __builtin_amdgcn_global_load_lds(
                (const __attribute__((address_space(1))) void*)(gbase + c * 256 + lane * 4),
                (__attribute__((address_space(3))) void*)(&xs[c * 256 + lane * 4]),
                16, 0, 0);
        }
    }

    // Constants pinned to SGPRs (readfirstlane) -> zero VGPR footprint in the loops.
    float G[36], w[6], wvs[6];
    #pragma unroll
    for (int i = 0; i < 36; ++i) G[i] = sconst(ws, i);
    #pragma unroll
    for (int i = 0; i < 6; ++i) w[i] = sconst(ws, 36 + i);
    #pragma unroll
    for (int i = 0; i < 6; ++i) wvs[i] = sconst(ws, 42 + i);
    const float bvs = sconst(ws, 48);

    __syncthreads();   // staging complete (sync waits vmcnt for global_load_lds)

    const int e = t >> 1;     // local element (pair-lanes share LDS rows -> broadcast)
    const int h = t & 1;      // which half of the 10 queries
    const float* xe = &xs[e * XFL];

    // Bulk LDS->reg: 15 x ds_read_b128 (base e*240 B, 16B-aligned). Only
    // compile-time indices into xv from here on (rule #20).
    float xv[XFL];
    const float4* xr = (const float4*)xe;
    #pragma unroll
    for (int i = 0; i < 15; ++i) {
        float4 v = xr[i];
        xv[4 * i + 0] = v.x;
        xv[4 * i + 1] = v.y;
        xv[4 * i + 2] = v.z;
        xv[4 * i + 3] = v.w;
    }

    // t_q for this thread's 5 queries. Query rows depend on runtime h -> read
    // them from LDS (dynamic base + constant offsets), NOT from xv.
    const float* xq0 = xe + h * (5 * D);
    float tq[5][6];
    #pragma unroll
    for (int j = 0; j < 5; ++j) {
        float xq[6];
        #pragma unroll
        for (int d = 0; d < 6; ++d) xq[d] = xq0[j * 6 + d];
        #pragma unroll
        for (int dp = 0; dp < 6; ++dp) {
            float s = 0.f;
            #pragma unroll
            for (int d = 0; d < 6; ++d) s += xq[d] * G[d * 6 + dp];
            tq[j][dp] = s;
        }
    }

    // Pure register math: scores + softmax + weighted vsum.
    float num[5] = {0.f, 0.f, 0.f, 0.f, 0.f};
    float den[5] = {0.f, 0.f, 0.f, 0.f, 0.f};
    #pragma unroll
    for (int k = 0; k < S; ++k) {
        float a = 0.f, vk = bvs;
        #pragma unroll
        for (int d = 0; d < 6; ++d) {
            a += w[d] * xv[k * 6 + d];
            vk += wvs[d] * xv[k * 6 + d];
        }
        #pragma unroll
        for (int j = 0; j < 5; ++j) {
            float s = a;
            #pragma unroll
            for (int d = 0; d < 6; ++d) s += tq[j][d] * xv[k * 6 + d];
            float ex = __builtin_amdgcn_exp2f(s);   // scores pre-scaled by log2e
            den[j] += ex;
            num[j] += ex * vk;
        }
    }

    // Thread's 5 outputs are contiguous: out flat idx = blk*1280 + t*5 + j
    float* op = out + (size_t)blk * (EPB * S) + t * 5;
    #pragma unroll
    for (int j = 0; j < 5; ++j) op[j] = num[j] * __builtin_amdgcn_rcpf(den[j]);
}

extern "C" void kernel_launch(void* const* d_in, const int* in_sizes, int n_in,
                              void* d_out, int out_size, void* d_ws, size_t ws_size,
                              hipStream_t stream) {
    const float* x  = (const float*)d_in[0];
    const float* Wk = (const float*)d_in[1];
    const float* bk = (const float*)d_in[2];
    const float* Wq = (const float*)d_in[3];
    const float* bq = (const float*)d_in[4];
    const float* Wv = (const float*)d_in[5];
    const float* bv = (const float*)d_in[6];
    float* out = (float*)d_out;
    float* ws  = (float*)d_ws;

    precompute_kernel<<<1, 64, 0, stream>>>(Wk, bk, Wq, bq, Wv, bv, ws);
    attn_kernel<<<NB / EPB, TPB, 0, stream>>>(x, ws, out);
}